// Round 1
// baseline (308.568 us; speedup 1.0000x reference)
//
#include <hip/hip_runtime.h>
#include <math.h>

// Problem constants
#define S_LEN   2048
#define D_MOD   512
#define N_HEADS 8
#define D_HEAD  64
#define FF_DIM  2048
#define M_ROWS  16384            // B*S
#define BHSD    8388608          // 8*8*2048*64 elements per Q/K/V tensor

typedef __attribute__((ext_vector_type(8))) __bf16 bf16x8;
typedef __attribute__((ext_vector_type(4))) float  f32x4;
typedef unsigned short u16;

__device__ __forceinline__ u16 f2bf(float f) {           // RNE f32 -> bf16 bits
  unsigned u = __float_as_uint(f);
  u += 0x7fffu + ((u >> 16) & 1u);
  return (u16)(u >> 16);
}

__device__ __forceinline__ f32x4 mfma16(bf16x8 a, bf16x8 b, f32x4 c) {
  return __builtin_amdgcn_mfma_f32_16x16x32_bf16(a, b, c, 0, 0, 0);
}

// async global->LDS, 16B per lane; lds base must be wave-uniform (HW adds lane*16)
__device__ __forceinline__ void async16(void* lds, const void* g) {
  __builtin_amdgcn_global_load_lds(
      (const __attribute__((address_space(1))) unsigned int*)g,
      (__attribute__((address_space(3))) unsigned int*)lds, 16, 0, 0);
}

// XOR swizzle within each 128B group of a 384B row (for 64x192 bf16 tiles)
__device__ __forceinline__ int swz384(int row, int bir) {
  return row * 384 + ((bir & ~127) | ((bir ^ ((row & 7) << 4)) & 127));
}

// ---------------- elementwise f32 -> bf16 ----------------
__global__ __launch_bounds__(256) void cvt_f32_bf16(const float* __restrict__ in,
                                                    u16* __restrict__ out, int n4) {
  int i = blockIdx.x * 256 + threadIdx.x;
  if (i < n4) {
    float4 v = reinterpret_cast<const float4*>(in)[i];
    ushort4 o;
    o.x = f2bf(v.x); o.y = f2bf(v.y); o.z = f2bf(v.z); o.w = f2bf(v.w);
    reinterpret_cast<ushort4*>(out)[i] = o;
  }
}

// ---------------- [K,N] f32 -> [N,K] bf16 transpose ----------------
__global__ void transpose_cvt(const float* __restrict__ in, u16* __restrict__ out,
                              int K, int N) {
  __shared__ float t[32][33];
  const int n0 = blockIdx.x * 32, k0 = blockIdx.y * 32;
  const int tx = threadIdx.x, ty = threadIdx.y;   // (32,8)
#pragma unroll
  for (int i = 0; i < 4; ++i)
    t[ty + 8 * i][tx] = in[(size_t)(k0 + ty + 8 * i) * N + n0 + tx];
  __syncthreads();
#pragma unroll
  for (int i = 0; i < 4; ++i)
    out[(size_t)(n0 + ty + 8 * i) * K + k0 + tx] = f2bf(t[tx][ty + 8 * i]);
}

// ---------------- gate = sigmoid(src @ Wg + bg), thresholded ----------------
__global__ __launch_bounds__(256) void gate_k(const float* __restrict__ src,
                                              const float* __restrict__ Wg,
                                              const float* __restrict__ bg,
                                              float* __restrict__ gate) {
  const int wid = threadIdx.x >> 6, lane = threadIdx.x & 63;
  const size_t row = (size_t)blockIdx.x * 4 + wid;
  const float4* s = reinterpret_cast<const float4*>(src + row * D_MOD);
  const float4* w = reinterpret_cast<const float4*>(Wg);
  float acc = 0.f;
#pragma unroll
  for (int i = 0; i < 2; ++i) {
    float4 a = s[lane * 2 + i], b = w[lane * 2 + i];
    acc += a.x * b.x + a.y * b.y + a.z * b.z + a.w * b.w;
  }
#pragma unroll
  for (int m = 1; m < 64; m <<= 1) acc += __shfl_xor(acc, m);
  if (lane == 0) {
    float g = 1.f / (1.f + expf(-(acc + bg[0])));
    gate[row] = g > 0.f ? g : 0.f;    // THRESH = 0
  }
}

// ---------------- layernorm over 512, one wave per row ----------------
template<bool WB>
__global__ __launch_bounds__(256) void ln_k(const float* __restrict__ in,
                                            const float* __restrict__ gam,
                                            const float* __restrict__ bet,
                                            float* __restrict__ outf,
                                            u16* __restrict__ outb) {
  const int wid = threadIdx.x >> 6, lane = threadIdx.x & 63;
  const size_t row = (size_t)blockIdx.x * 4 + wid;
  const float4* p = reinterpret_cast<const float4*>(in + row * D_MOD);
  float4 v0 = p[lane * 2], v1 = p[lane * 2 + 1];
  float s  = v0.x + v0.y + v0.z + v0.w + v1.x + v1.y + v1.z + v1.w;
  float s2 = v0.x * v0.x + v0.y * v0.y + v0.z * v0.z + v0.w * v0.w +
             v1.x * v1.x + v1.y * v1.y + v1.z * v1.z + v1.w * v1.w;
#pragma unroll
  for (int m = 1; m < 64; m <<= 1) { s += __shfl_xor(s, m); s2 += __shfl_xor(s2, m); }
  const float mu = s * (1.0f / 512.0f);
  const float var = s2 * (1.0f / 512.0f) - mu * mu;
  const float rs = 1.0f / sqrtf(var + 1e-5f);
  const float4* gp = reinterpret_cast<const float4*>(gam);
  const float4* bp = reinterpret_cast<const float4*>(bet);
  float4 g0 = gp[lane * 2], g1 = gp[lane * 2 + 1];
  float4 b0 = bp[lane * 2], b1 = bp[lane * 2 + 1];
  float4 o0, o1;
  o0.x = (v0.x - mu) * rs * g0.x + b0.x;  o0.y = (v0.y - mu) * rs * g0.y + b0.y;
  o0.z = (v0.z - mu) * rs * g0.z + b0.z;  o0.w = (v0.w - mu) * rs * g0.w + b0.w;
  o1.x = (v1.x - mu) * rs * g1.x + b1.x;  o1.y = (v1.y - mu) * rs * g1.y + b1.y;
  o1.z = (v1.z - mu) * rs * g1.z + b1.z;  o1.w = (v1.w - mu) * rs * g1.w + b1.w;
  float4* q = reinterpret_cast<float4*>(outf + row * D_MOD);
  q[lane * 2] = o0; q[lane * 2 + 1] = o1;
  if constexpr (WB) {
    ushort4 h0, h1;
    h0.x = f2bf(o0.x); h0.y = f2bf(o0.y); h0.z = f2bf(o0.z); h0.w = f2bf(o0.w);
    h1.x = f2bf(o1.x); h1.y = f2bf(o1.y); h1.z = f2bf(o1.z); h1.w = f2bf(o1.w);
    ushort4* ob = reinterpret_cast<ushort4*>(outb + row * D_MOD);
    ob[lane * 2] = h0; ob[lane * 2 + 1] = h1;
  }
}

// ---------------- GEMM: C = A[M,K] @ Bt[N,K]^T, fused epilogues ----------------
struct EpiArgs {
  const float* b0; const float* b1; const float* b2;   // biases
  const float* add;                                    // residual (f32 [M,N])
  const float* gate;                                   // [M]
  float* outf; u16* outb;
};

// EPI: 0 = QKV bias+scatter->bf16[B,H,S,dh]   1 = src + gate*(acc+bo) -> f32
//      2 = relu(acc+b1) -> bf16               3 = add + acc + b2 -> f32
template<int EPI>
__global__ __launch_bounds__(256)
void gemm_bt(const u16* __restrict__ A, const u16* __restrict__ Bt,
             int N, int K, EpiArgs e) {
  __shared__ __align__(16) u16 As[128 * 64];
  __shared__ __align__(16) u16 Bs[128 * 64];
  const int tid = threadIdx.x;
  const int wid = tid >> 6, lane = tid & 63;
  const int wr = wid >> 1, wc = wid & 1;
  const int sub = lane >> 4, lc = lane & 15;
  const int m0 = blockIdx.y * 128, n0 = blockIdx.x * 128;

  f32x4 acc[4][4];
#pragma unroll
  for (int i = 0; i < 4; ++i)
#pragma unroll
    for (int j = 0; j < 4; ++j) acc[i][j] = (f32x4){0.f, 0.f, 0.f, 0.f};

  for (int k0 = 0; k0 < K; k0 += 64) {
#pragma unroll
    for (int i = 0; i < 4; ++i) {
      const int ldso = (wid * 4 + i) * 1024;       // wave-uniform LDS byte base
      const int o = ldso + lane * 16;              // this lane's content offset
      const int r = o >> 7;                        // tile row (128B per row)
      const int c = (o & 127) >> 1;                // element within row
      async16((char*)As + ldso, A  + (size_t)(m0 + r) * K + k0 + c);
      async16((char*)Bs + ldso, Bt + (size_t)(n0 + r) * K + k0 + c);
    }
    __syncthreads();                               // compiler drains vmcnt before barrier
#pragma unroll
    for (int ks = 0; ks < 2; ++ks) {
      bf16x8 a[4], b[4];
#pragma unroll
      for (int i = 0; i < 4; ++i)
        a[i] = *reinterpret_cast<const bf16x8*>(&As[(wr * 64 + i * 16 + lc) * 64 + ks * 32 + sub * 8]);
#pragma unroll
      for (int j = 0; j < 4; ++j)
        b[j] = *reinterpret_cast<const bf16x8*>(&Bs[(wc * 64 + j * 16 + lc) * 64 + ks * 32 + sub * 8]);
#pragma unroll
      for (int i = 0; i < 4; ++i)
#pragma unroll
        for (int j = 0; j < 4; ++j) acc[i][j] = mfma16(a[i], b[j], acc[i][j]);
    }
    __syncthreads();
  }

#pragma unroll
  for (int i = 0; i < 4; ++i) {
    const int row0 = m0 + wr * 64 + i * 16 + sub * 4;
#pragma unroll
    for (int j = 0; j < 4; ++j) {
      const int col = n0 + wc * 64 + j * 16 + lc;
      f32x4 v = acc[i][j];
#pragma unroll
      for (int r = 0; r < 4; ++r) {
        const int row = row0 + r;
        const float val = v[r];
        if constexpr (EPI == 0) {
          const int which = col >> 9, nn = col & 511;
          const int hh = nn >> 6, dd = nn & 63;
          const float* bp = (which == 0) ? e.b0 : (which == 1) ? e.b1 : e.b2;
          const int bb = row >> 11, ss = row & 2047;
          e.outb[(size_t)which * BHSD + (((size_t)bb * N_HEADS + hh) * S_LEN + ss) * D_HEAD + dd]
              = f2bf(val + bp[nn]);
        } else if constexpr (EPI == 1) {
          e.outf[(size_t)row * D_MOD + col] =
              e.add[(size_t)row * D_MOD + col] + e.gate[row] * (val + e.b0[col]);
        } else if constexpr (EPI == 2) {
          float o = val + e.b0[col];
          e.outb[(size_t)row * FF_DIM + col] = f2bf(o > 0.f ? o : 0.f);
        } else {
          e.outf[(size_t)row * D_MOD + col] =
              e.add[(size_t)row * D_MOD + col] + val + e.b0[col];
        }
      }
    }
  }
}

// ---------------- windowed attention: one block per (b,h, 64-query tile) ----------------
__global__ __launch_bounds__(256)
void attn_k(const u16* __restrict__ Q, const u16* __restrict__ Kt,
            const u16* __restrict__ V, u16* __restrict__ Oflat) {
  __shared__ __align__(16) u16 VT[64 * 192];   // V^T (swizzled): row=d, col=key
  __shared__ __align__(16) u16 P [64 * 192];   // probs (swizzled): row=q, col=key
  __shared__ float tab[256];                   // bias table indexed by dist+127
  const int tid = threadIdx.x;
  const int wid = tid >> 6, lane = tid & 63;
  const int sub = lane >> 4, lc = lane & 15;
  const int qb = blockIdx.x, bh = blockIdx.y;
  const int bb = bh >> 3, hh = bh & 7;
  const int q0 = qb * 64, kstart = q0 - 64;    // 192-key band
  const u16* Qb = Q  + (size_t)bh * S_LEN * D_HEAD;
  const u16* Kb = Kt + (size_t)bh * S_LEN * D_HEAD;
  const u16* Vb = V  + (size_t)bh * S_LEN * D_HEAD;

  if (tid < 255) {                             // dist in [-127,127]
    const int di = tid - 127;
    const float fd = (float)di;
    tab[tid] = (di >= -64 && di <= 64)
        ? expf(-fd * fd * 0.125f) + cosf(0.06283185307179586f * fd)   // gauss + periodic
        : -1e9f;                                                       // out of window
  }

  // stage V^T (zero-fill out-of-range keys)
#pragma unroll
  for (int i = 0; i < 6; ++i) {
    const int c = tid + 256 * i;               // 1536 chunks of 8 elements
    const int kk = c >> 3, dc = (c & 7) * 8;
    const int kg = kstart + kk;
    uint4 val = {0u, 0u, 0u, 0u};
    if (kg >= 0 && kg < S_LEN)
      val = *reinterpret_cast<const uint4*>(Vb + (size_t)kg * D_HEAD + dc);
    const u16* pv = reinterpret_cast<const u16*>(&val);
#pragma unroll
    for (int j = 0; j < 8; ++j)
      *reinterpret_cast<u16*>(reinterpret_cast<char*>(VT) + swz384(dc + j, kk * 2)) = pv[j];
  }

  // Q fragments straight from global (A operand: row = lane&15)
  bf16x8 qf[2];
#pragma unroll
  for (int ks = 0; ks < 2; ++ks)
    qf[ks] = *reinterpret_cast<const bf16x8*>(Qb + (size_t)(q0 + wid * 16 + lc) * D_HEAD + ks * 32 + sub * 8);

  // QK^T: 12 col tiles of 16 keys, K fragments straight from global (clamped; masked later)
  f32x4 sc[12];
#pragma unroll
  for (int t = 0; t < 12; ++t) sc[t] = (f32x4){0.f, 0.f, 0.f, 0.f};
#pragma unroll
  for (int ks = 0; ks < 2; ++ks)
#pragma unroll
    for (int t = 0; t < 12; ++t) {
      int kg = kstart + t * 16 + lc;
      int kc = kg < 0 ? 0 : (kg > S_LEN - 1 ? S_LEN - 1 : kg);
      bf16x8 kf = *reinterpret_cast<const bf16x8*>(Kb + (size_t)kc * D_HEAD + ks * 32 + sub * 8);
      sc[t] = mfma16(qf[ks], kf, sc[t]);
    }
  __syncthreads();   // tab + VT ready

  // bias + mask + wave-parallel softmax (row lives across 16 lanes x 12 regs)
  float rmax[4] = {-3e38f, -3e38f, -3e38f, -3e38f};
#pragma unroll
  for (int t = 0; t < 12; ++t) {
    const int kk = t * 16 + lc;
    const int kg = kstart + kk;
    const bool valid = (kg >= 0) && (kg < S_LEN);
#pragma unroll
    for (int r = 0; r < 4; ++r) {
      const int qrow = wid * 16 + sub * 4 + r;
      const float bias = valid ? tab[qrow - kk + 191] : -1e9f;
      const float sv = sc[t][r] * 0.125f + bias;   // 1/sqrt(64)
      sc[t][r] = sv;
      rmax[r] = fmaxf(rmax[r], sv);
    }
  }
#pragma unroll
  for (int m = 1; m < 16; m <<= 1)
#pragma unroll
    for (int r = 0; r < 4; ++r) rmax[r] = fmaxf(rmax[r], __shfl_xor(rmax[r], m));
  float rsum[4] = {0.f, 0.f, 0.f, 0.f};
#pragma unroll
  for (int t = 0; t < 12; ++t)
#pragma unroll
    for (int r = 0; r < 4; ++r) {
      const float p = expf(sc[t][r] - rmax[r]);
      sc[t][r] = p; rsum[r] += p;
    }
#pragma unroll
  for (int m = 1; m < 16; m <<= 1)
#pragma unroll
    for (int r = 0; r < 4; ++r) rsum[r] += __shfl_xor(rsum[r], m);
  float rinv[4];
#pragma unroll
  for (int r = 0; r < 4; ++r) rinv[r] = 1.0f / rsum[r];
#pragma unroll
  for (int t = 0; t < 12; ++t)
#pragma unroll
    for (int r = 0; r < 4; ++r) {
      const int qrow = wid * 16 + sub * 4 + r;
      *reinterpret_cast<u16*>(reinterpret_cast<char*>(P) + swz384(qrow, (t * 16 + lc) * 2))
          = f2bf(sc[t][r] * rinv[r]);
    }
  __syncthreads();   // P + VT consumable

  // PV: out[64q][64d], K-dim = 192 keys
  f32x4 oacc[4];
#pragma unroll
  for (int t = 0; t < 4; ++t) oacc[t] = (f32x4){0.f, 0.f, 0.f, 0.f};
  const int arow = wid * 16 + lc;
#pragma unroll
  for (int ks = 0; ks < 6; ++ks) {
    const int bir = ks * 64 + sub * 16;
    bf16x8 pa = *reinterpret_cast<const bf16x8*>(reinterpret_cast<char*>(P) + swz384(arow, bir));
#pragma unroll
    for (int t = 0; t < 4; ++t) {
      bf16x8 vb = *reinterpret_cast<const bf16x8*>(reinterpret_cast<char*>(VT) + swz384(t * 16 + lc, bir));
      oacc[t] = mfma16(pa, vb, oacc[t]);
    }
  }

  // write to [B,S,H*dh] bf16
  const size_t obase = ((size_t)bb * S_LEN + q0) * D_MOD + hh * D_HEAD;
#pragma unroll
  for (int t = 0; t < 4; ++t)
#pragma unroll
    for (int r = 0; r < 4; ++r) {
      const int qrow = wid * 16 + sub * 4 + r;
      Oflat[obase + (size_t)qrow * D_MOD + t * 16 + lc] = f2bf(oacc[t][r]);
    }
}

// ---------------- launch ----------------
extern "C" void kernel_launch(void* const* d_in, const int* in_sizes, int n_in,
                              void* d_out, int out_size, void* d_ws, size_t ws_size,
                              hipStream_t stream) {
  (void)in_sizes; (void)n_in; (void)out_size; (void)ws_size;
  const float* src  = (const float*)d_in[0];
  const float* Wq   = (const float*)d_in[1];
  const float* bq   = (const float*)d_in[2];
  const float* Wk   = (const float*)d_in[3];
  const float* bk   = (const float*)d_in[4];
  const float* Wv   = (const float*)d_in[5];
  const float* bv   = (const float*)d_in[6];
  const float* Wo   = (const float*)d_in[7];
  const float* bo   = (const float*)d_in[8];
  const float* Wg   = (const float*)d_in[9];
  const float* bg   = (const float*)d_in[10];
  const float* W1   = (const float*)d_in[11];
  const float* b1   = (const float*)d_in[12];
  const float* W2   = (const float*)d_in[13];
  const float* b2   = (const float*)d_in[14];
  const float* ln1g = (const float*)d_in[15];
  const float* ln1b = (const float*)d_in[16];
  const float* ln2g = (const float*)d_in[17];
  const float* ln2b = (const float*)d_in[18];
  float* out = (float*)d_out;

  char* ws = (char*)d_ws;
  u16*   Xbf    = (u16*)  (ws + 0);           // 16,777,216 B
  u16*   WqkvT  = (u16*)  (ws + 16777216);    //  1,572,864
  u16*   WoT    = (u16*)  (ws + 18350080);    //    524,288
  u16*   W1T    = (u16*)  (ws + 18874368);    //  2,097,152
  u16*   W2T    = (u16*)  (ws + 20971520);    //  2,097,152
  float* gatef  = (float*)(ws + 23068672);    //     65,536
  u16*   QKVbf  = (u16*)  (ws + 23134208);    // 50,331,648
  u16*   attnfl = (u16*)  (ws + 73465856);    // 16,777,216
  u16*   hbuf   = QKVbf;                      // reuse QKV+attnfl = 67,108,864 (dead by then)
  float* y1     = (float*)(ws + 90243072);    // 33,554,432
  float* zf     = y1;                         // reuse after LN1
  float* xf     = (float*)(ws + 123797504);   // 33,554,432
  u16*   xbf2   = (u16*)  (ws + 157351936);   // 16,777,216  (total 174,129,152)

  dim3 tb(32, 8);
  cvt_f32_bf16<<<8192, 256, 0, stream>>>(src, Xbf, M_ROWS * D_MOD / 4);
  transpose_cvt<<<dim3(16, 16), tb, 0, stream>>>(Wq, WqkvT,             512, 512);
  transpose_cvt<<<dim3(16, 16), tb, 0, stream>>>(Wk, WqkvT + 512 * 512, 512, 512);
  transpose_cvt<<<dim3(16, 16), tb, 0, stream>>>(Wv, WqkvT + 2 * 512 * 512, 512, 512);
  transpose_cvt<<<dim3(16, 16), tb, 0, stream>>>(Wo, WoT, 512, 512);
  transpose_cvt<<<dim3(64, 16), tb, 0, stream>>>(W1, W1T, 512, 2048);
  transpose_cvt<<<dim3(16, 64), tb, 0, stream>>>(W2, W2T, 2048, 512);
  gate_k<<<4096, 256, 0, stream>>>(src, Wg, bg, gatef);

  EpiArgs e1{bq, bk, bv, nullptr, nullptr, nullptr, QKVbf};
  gemm_bt<0><<<dim3(12, 128), 256, 0, stream>>>(Xbf, WqkvT, 1536, 512, e1);

  attn_k<<<dim3(32, 64), 256, 0, stream>>>(QKVbf, QKVbf + BHSD, QKVbf + 2 * BHSD, attnfl);

  EpiArgs e2{bo, nullptr, nullptr, src, gatef, y1, nullptr};
  gemm_bt<1><<<dim3(4, 128), 256, 0, stream>>>(attnfl, WoT, 512, 512, e2);

  ln_k<true><<<4096, 256, 0, stream>>>(y1, ln1g, ln1b, xf, xbf2);

  EpiArgs e3{b1, nullptr, nullptr, nullptr, nullptr, nullptr, hbuf};
  gemm_bt<2><<<dim3(16, 128), 256, 0, stream>>>(xbf2, W1T, 2048, 512, e3);

  EpiArgs e4{b2, nullptr, nullptr, xf, nullptr, zf, nullptr};
  gemm_bt<3><<<dim3(4, 128), 256, 0, stream>>>(hbuf, W2T, 512, 2048, e4);

  ln_k<false><<<4096, 256, 0, stream>>>(zf, ln2g, ln2b, out, nullptr);
}

// Round 2
// 234.961 us; speedup vs baseline: 1.3133x; 1.3133x over previous
//
#include <hip/hip_runtime.h>
#include <hip/hip_bf16.h>
#include <math.h>

// Problem constants
#define S_LEN   2048
#define D_MOD   512
#define N_HEADS 8
#define D_HEAD  64
#define FF_DIM  2048
#define M_ROWS  16384            // B*S
#define BHSD    8388608          // 8*8*2048*64 elements per Q/K/V tensor

typedef __attribute__((ext_vector_type(8))) __bf16 bf16x8;
typedef __attribute__((ext_vector_type(4))) float  f32x4;
typedef unsigned short u16;

__device__ __forceinline__ u16 f2bf(float f) {           // RNE f32 -> bf16 bits
  unsigned u = __float_as_uint(f);
  u += 0x7fffu + ((u >> 16) & 1u);
  return (u16)(u >> 16);
}
__device__ __forceinline__ float bf2f(u16 h) { return __uint_as_float(((unsigned)h) << 16); }

__device__ __forceinline__ f32x4 mfma16(bf16x8 a, bf16x8 b, f32x4 c) {
  return __builtin_amdgcn_mfma_f32_16x16x32_bf16(a, b, c, 0, 0, 0);
}

// async global->LDS, 16B per lane; lds base wave-uniform (HW adds lane*16)
__device__ __forceinline__ void async16(void* lds, const void* g) {
  __builtin_amdgcn_global_load_lds(
      (const __attribute__((address_space(1))) unsigned int*)g,
      (__attribute__((address_space(3))) unsigned int*)lds, 16, 0, 0);
}

#define BAR()    asm volatile("s_barrier" ::: "memory")
#define WAITV(n) asm volatile("s_waitcnt vmcnt(" #n ")" ::: "memory")
#define WAITL()  asm volatile("s_waitcnt lgkmcnt(0)" ::: "memory")

// XOR swizzle within each 128B group of a 384B row (attn 64x192 bf16 tiles)
__device__ __forceinline__ int swz384(int row, int bir) {
  return row * 384 + ((bir & ~127) | ((bir ^ ((row & 7) << 4)) & 127));
}

// ---------------- fused src->bf16 + gate, one wave per row ----------------
__global__ __launch_bounds__(256) void cvt_gate(const float* __restrict__ src,
                                                const float* __restrict__ Wg,
                                                const float* __restrict__ bg,
                                                u16* __restrict__ xb,
                                                float* __restrict__ gate) {
  const int wid = threadIdx.x >> 6, lane = threadIdx.x & 63;
  const size_t row = (size_t)blockIdx.x * 4 + wid;
  const float4* s = reinterpret_cast<const float4*>(src + row * D_MOD);
  const float4* w = reinterpret_cast<const float4*>(Wg);
  float4 a0 = s[lane * 2], a1 = s[lane * 2 + 1];
  float4 w0 = w[lane * 2], w1 = w[lane * 2 + 1];
  float acc = a0.x * w0.x + a0.y * w0.y + a0.z * w0.z + a0.w * w0.w +
              a1.x * w1.x + a1.y * w1.y + a1.z * w1.z + a1.w * w1.w;
#pragma unroll
  for (int m = 1; m < 64; m <<= 1) acc += __shfl_xor(acc, m);
  ushort4 h0, h1;
  h0.x = f2bf(a0.x); h0.y = f2bf(a0.y); h0.z = f2bf(a0.z); h0.w = f2bf(a0.w);
  h1.x = f2bf(a1.x); h1.y = f2bf(a1.y); h1.z = f2bf(a1.z); h1.w = f2bf(a1.w);
  ushort4* ob = reinterpret_cast<ushort4*>(xb + row * D_MOD);
  ob[lane * 2] = h0; ob[lane * 2 + 1] = h1;
  if (lane == 0) {
    float g = 1.f / (1.f + expf(-(acc + bg[0])));
    gate[row] = g > 0.f ? g : 0.f;    // THRESH = 0
  }
}

// ---------------- [K,N] f32 -> [N,K] bf16 transpose ----------------
__global__ void transpose_cvt(const float* __restrict__ in, u16* __restrict__ out,
                              int K, int N) {
  __shared__ float t[32][33];
  const int n0 = blockIdx.x * 32, k0 = blockIdx.y * 32;
  const int tx = threadIdx.x, ty = threadIdx.y;   // (32,8)
#pragma unroll
  for (int i = 0; i < 4; ++i)
    t[ty + 8 * i][tx] = in[(size_t)(k0 + ty + 8 * i) * N + n0 + tx];
  __syncthreads();
#pragma unroll
  for (int i = 0; i < 4; ++i)
    out[(size_t)(n0 + ty + 8 * i) * K + k0 + tx] = f2bf(t[tx][ty + 8 * i]);
}

// ---------------- layernorm 1: f32 in -> bf16 out, one wave per row ----------------
__global__ __launch_bounds__(256) void ln1_k(const float* __restrict__ in,
                                             const float* __restrict__ gam,
                                             const float* __restrict__ bet,
                                             u16* __restrict__ outb) {
  const int wid = threadIdx.x >> 6, lane = threadIdx.x & 63;
  const size_t row = (size_t)blockIdx.x * 4 + wid;
  const float4* p = reinterpret_cast<const float4*>(in + row * D_MOD);
  float4 v0 = p[lane * 2], v1 = p[lane * 2 + 1];
  float s  = v0.x + v0.y + v0.z + v0.w + v1.x + v1.y + v1.z + v1.w;
  float s2 = v0.x * v0.x + v0.y * v0.y + v0.z * v0.z + v0.w * v0.w +
             v1.x * v1.x + v1.y * v1.y + v1.z * v1.z + v1.w * v1.w;
#pragma unroll
  for (int m = 1; m < 64; m <<= 1) { s += __shfl_xor(s, m); s2 += __shfl_xor(s2, m); }
  const float mu = s * (1.0f / 512.0f);
  const float var = s2 * (1.0f / 512.0f) - mu * mu;
  const float rs = 1.0f / sqrtf(var + 1e-5f);
  const float4* gp = reinterpret_cast<const float4*>(gam);
  const float4* bp = reinterpret_cast<const float4*>(bet);
  float4 g0 = gp[lane * 2], g1 = gp[lane * 2 + 1];
  float4 b0 = bp[lane * 2], b1 = bp[lane * 2 + 1];
  ushort4 h0, h1;
  h0.x = f2bf((v0.x - mu) * rs * g0.x + b0.x);  h0.y = f2bf((v0.y - mu) * rs * g0.y + b0.y);
  h0.z = f2bf((v0.z - mu) * rs * g0.z + b0.z);  h0.w = f2bf((v0.w - mu) * rs * g0.w + b0.w);
  h1.x = f2bf((v1.x - mu) * rs * g1.x + b1.x);  h1.y = f2bf((v1.y - mu) * rs * g1.y + b1.y);
  h1.z = f2bf((v1.z - mu) * rs * g1.z + b1.z);  h1.w = f2bf((v1.w - mu) * rs * g1.w + b1.w);
  ushort4* ob = reinterpret_cast<ushort4*>(outb + row * D_MOD);
  ob[lane * 2] = h0; ob[lane * 2 + 1] = h1;
}

// ---------------- fused split-K reduce + bias + residual + layernorm 2 ----------------
__global__ __launch_bounds__(256) void ln2red_k(const u16* __restrict__ xb,
                                                const float* __restrict__ p0,
                                                const float* __restrict__ p1,
                                                const float* __restrict__ b2,
                                                const float* __restrict__ gam,
                                                const float* __restrict__ bet,
                                                float* __restrict__ out) {
  const int wid = threadIdx.x >> 6, lane = threadIdx.x & 63;
  const size_t row = (size_t)blockIdx.x * 4 + wid;
  const size_t base = row * D_MOD;
  const ushort4* xp = reinterpret_cast<const ushort4*>(xb + base);
  const float4* q0 = reinterpret_cast<const float4*>(p0 + base);
  const float4* q1 = reinterpret_cast<const float4*>(p1 + base);
  const float4* bb = reinterpret_cast<const float4*>(b2);
  ushort4 h0 = xp[lane * 2], h1 = xp[lane * 2 + 1];
  float4 a0 = q0[lane * 2], a1 = q0[lane * 2 + 1];
  float4 c0 = q1[lane * 2], c1 = q1[lane * 2 + 1];
  float4 d0 = bb[lane * 2], d1 = bb[lane * 2 + 1];
  float4 v0, v1;
  v0.x = bf2f(h0.x) + a0.x + c0.x + d0.x;  v0.y = bf2f(h0.y) + a0.y + c0.y + d0.y;
  v0.z = bf2f(h0.z) + a0.z + c0.z + d0.z;  v0.w = bf2f(h0.w) + a0.w + c0.w + d0.w;
  v1.x = bf2f(h1.x) + a1.x + c1.x + d1.x;  v1.y = bf2f(h1.y) + a1.y + c1.y + d1.y;
  v1.z = bf2f(h1.z) + a1.z + c1.z + d1.z;  v1.w = bf2f(h1.w) + a1.w + c1.w + d1.w;
  float s  = v0.x + v0.y + v0.z + v0.w + v1.x + v1.y + v1.z + v1.w;
  float s2 = v0.x * v0.x + v0.y * v0.y + v0.z * v0.z + v0.w * v0.w +
             v1.x * v1.x + v1.y * v1.y + v1.z * v1.z + v1.w * v1.w;
#pragma unroll
  for (int m = 1; m < 64; m <<= 1) { s += __shfl_xor(s, m); s2 += __shfl_xor(s2, m); }
  const float mu = s * (1.0f / 512.0f);
  const float var = s2 * (1.0f / 512.0f) - mu * mu;
  const float rs = 1.0f / sqrtf(var + 1e-5f);
  const float4* gp = reinterpret_cast<const float4*>(gam);
  const float4* bp = reinterpret_cast<const float4*>(bet);
  float4 g0 = gp[lane * 2], g1 = gp[lane * 2 + 1];
  float4 e0 = bp[lane * 2], e1 = bp[lane * 2 + 1];
  float4 o0, o1;
  o0.x = (v0.x - mu) * rs * g0.x + e0.x;  o0.y = (v0.y - mu) * rs * g0.y + e0.y;
  o0.z = (v0.z - mu) * rs * g0.z + e0.z;  o0.w = (v0.w - mu) * rs * g0.w + e0.w;
  o1.x = (v1.x - mu) * rs * g1.x + e1.x;  o1.y = (v1.y - mu) * rs * g1.y + e1.y;
  o1.z = (v1.z - mu) * rs * g1.z + e1.z;  o1.w = (v1.w - mu) * rs * g1.w + e1.w;
  float4* q = reinterpret_cast<float4*>(out + base);
  q[lane * 2] = o0; q[lane * 2 + 1] = o1;
}

// ---------------- 256x256 deep-pipelined GEMM: C = A[M,K] @ Bt[N,K]^T ----------------
struct EpiArgs {
  const float* b0; const float* b1; const float* b2;   // biases
  const float* add; const float* gate;
  float* outf; float* outf2; u16* outb;
};

// EPI: 0 = QKV bias+scatter->bf16[3][B,H,S,dh]   2 = relu(acc+b1)->bf16 [M,2048]
//      4 = raw partial f32 -> outf (bz=0) / outf2 (bz=1), stride 512
template<int EPI, int LD, int NT, int KSLICE, int GX, int GY>
__device__ __forceinline__ void gemm256_body(const u16* __restrict__ A,
                                             const u16* __restrict__ Bt, EpiArgs e) {
  extern __shared__ char smem[];
  char* Asb = smem;            // [2 buf][256 rows][128 B], row-swizzled via source
  char* Bsb = smem + 65536;
  const int tid = threadIdx.x;
  const int wid = tid >> 6, lane = tid & 63;
  const int sub = lane >> 4, lc = lane & 15;
  const int wr = wid >> 2, wcn = wid & 3;

  // flatten + bijective XCD swizzle (all grids are multiples of 8 blocks)
  const int nwg = (int)(gridDim.x * gridDim.y * gridDim.z);
  const int orig = ((int)blockIdx.z * (int)gridDim.y + (int)blockIdx.y) * (int)gridDim.x + (int)blockIdx.x;
  const int cpx = nwg >> 3;
  const int wg = (orig & 7) * cpx + (orig >> 3);
  const int bx = wg % GX;
  const int by = (wg / GX) % GY;
  const int bz = wg / (GX * GY);
  const int m0 = by * 256, n0 = bx * 256;
  const int kb = KSLICE * bz;

  const u16* Ab = A + (size_t)m0 * LD;
  const u16* Bb = Bt + (size_t)n0 * LD;

  f32x4 acc[8][4];
#pragma unroll
  for (int i = 0; i < 8; ++i)
#pragma unroll
    for (int j = 0; j < 4; ++j) acc[i][j] = (f32x4){0.f, 0.f, 0.f, 0.f};

  const int lr0 = tid >> 3;   // 0..63
  const int sl  = tid & 7;

  // stage one 256x64 bf16 tile (A or B): 4 x async16 per thread, source pre-swizzled
#define STAGE(BASE, SRC, BUF, KT)                                              \
  {                                                                            \
    const int kk_ = kb + (KT) * 64;                                            \
    _Pragma("unroll")                                                          \
    for (int r_ = 0; r_ < 4; ++r_) {                                           \
      const int lr_ = r_ * 64 + lr0;                                           \
      async16((BASE) + (BUF) * 32768 + r_ * 8192 + wid * 1024,                 \
              (SRC) + (size_t)lr_ * LD + kk_ + ((sl ^ (lr_ & 7)) << 3));       \
    }                                                                          \
  }
#define LDFRAG(BASE, ROW, KS) \
  (*reinterpret_cast<const bf16x8*>((BASE) + (ROW) * 128 + ((((KS) * 64) + sub * 16) ^ (((ROW) & 7) << 4))))

  // prologue: B0,A0,B1,A1 (issue order matters for vmcnt counting)
  STAGE(Bsb, Bb, 0, 0);
  STAGE(Asb, Ab, 0, 0);
  STAGE(Bsb, Bb, 1, 1);
  STAGE(Asb, Ab, 1, 1);
  WAITV(8);            // tile 0 landed, tile 1's 8 loads still in flight
  BAR();

  for (int t = 0; t < NT; ++t) {
    const int buf = t & 1;
    char* Abl = Asb + buf * 32768;
    char* Bbl = Bsb + buf * 32768;
    bf16x8 af[4][2], bfr[2][2][2];   // af: qr-half of A; bfr[qc][fc][ks]
    // ---- ph1: read A qr0 (8) + B qc0 (4); MFMA (qr0,qc0) ----
#pragma unroll
    for (int f = 0; f < 4; ++f) {
      const int row = wr * 128 + f * 16 + lc;
#pragma unroll
      for (int ks = 0; ks < 2; ++ks) af[f][ks] = LDFRAG(Abl, row, ks);
    }
#pragma unroll
    for (int f = 0; f < 2; ++f) {
      const int row = wcn * 64 + f * 16 + lc;
#pragma unroll
      for (int ks = 0; ks < 2; ++ks) bfr[0][f][ks] = LDFRAG(Bbl, row, ks);
    }
    __builtin_amdgcn_s_setprio(1);
#pragma unroll
    for (int f = 0; f < 4; ++f)
#pragma unroll
      for (int c = 0; c < 2; ++c)
#pragma unroll
        for (int ks = 0; ks < 2; ++ks)
          acc[f][c] = mfma16(af[f][ks], bfr[0][c][ks], acc[f][c]);
    __builtin_amdgcn_s_setprio(0);
    BAR();
    // ---- ph2: read B qc1 (4); MFMA (qr0,qc1) ----
#pragma unroll
    for (int f = 0; f < 2; ++f) {
      const int row = wcn * 64 + 32 + f * 16 + lc;
#pragma unroll
      for (int ks = 0; ks < 2; ++ks) bfr[1][f][ks] = LDFRAG(Bbl, row, ks);
    }
    __builtin_amdgcn_s_setprio(1);
#pragma unroll
    for (int f = 0; f < 4; ++f)
#pragma unroll
      for (int c = 0; c < 2; ++c)
#pragma unroll
        for (int ks = 0; ks < 2; ++ks)
          acc[f][2 + c] = mfma16(af[f][ks], bfr[1][c][ks], acc[f][2 + c]);
    __builtin_amdgcn_s_setprio(0);
    WAITL();           // all B (and A) LDS reads landed in regs before B region is re-staged
    BAR();
    // ---- ph3: stage B(t+2) into this buf; read A qr1 (8); MFMA (qr1,qc1) ----
    if (t + 2 < NT) STAGE(Bsb, Bb, buf, t + 2);
#pragma unroll
    for (int f = 0; f < 4; ++f) {
      const int row = wr * 128 + 64 + f * 16 + lc;
#pragma unroll
      for (int ks = 0; ks < 2; ++ks) af[f][ks] = LDFRAG(Abl, row, ks);
    }
    __builtin_amdgcn_s_setprio(1);
#pragma unroll
    for (int f = 0; f < 4; ++f)
#pragma unroll
      for (int c = 0; c < 2; ++c)
#pragma unroll
        for (int ks = 0; ks < 2; ++ks)
          acc[4 + f][2 + c] = mfma16(af[f][ks], bfr[1][c][ks], acc[4 + f][2 + c]);
    __builtin_amdgcn_s_setprio(0);
    WAITL();           // A qr1 reads landed before A region is re-staged
    BAR();
    // ---- ph4: stage A(t+2); MFMA (qr1,qc0); counted boundary wait ----
    if (t + 2 < NT) STAGE(Asb, Ab, buf, t + 2);
    __builtin_amdgcn_s_setprio(1);
#pragma unroll
    for (int f = 0; f < 4; ++f)
#pragma unroll
      for (int c = 0; c < 2; ++c)
#pragma unroll
        for (int ks = 0; ks < 2; ++ks)
          acc[4 + f][c] = mfma16(af[f][ks], bfr[0][c][ks], acc[4 + f][c]);
    __builtin_amdgcn_s_setprio(0);
    if (t + 1 < NT) {
      if (t + 2 < NT) { WAITV(8); } else { WAITV(0); }  // leave next-next tile in flight
      BAR();
    }
  }
#undef STAGE
#undef LDFRAG

  // epilogue
#pragma unroll
  for (int fr = 0; fr < 8; ++fr) {
    const int row0 = m0 + wr * 128 + fr * 16 + sub * 4;
#pragma unroll
    for (int fc = 0; fc < 4; ++fc) {
      const int col = n0 + wcn * 64 + fc * 16 + lc;
      f32x4 v = acc[fr][fc];
#pragma unroll
      for (int i = 0; i < 4; ++i) {
        const int row = row0 + i;
        const float val = v[i];
        if constexpr (EPI == 0) {
          const int which = col >> 9, nn = col & 511;
          const int hh = nn >> 6, dd = nn & 63;
          const float* bp = (which == 0) ? e.b0 : (which == 1) ? e.b1 : e.b2;
          const int bb = row >> 11, ss = row & 2047;
          e.outb[(size_t)which * BHSD + (((size_t)bb * N_HEADS + hh) * S_LEN + ss) * D_HEAD + dd]
              = f2bf(val + bp[nn]);
        } else if constexpr (EPI == 2) {
          float o = val + e.b0[col];
          e.outb[(size_t)row * FF_DIM + col] = f2bf(o > 0.f ? o : 0.f);
        } else {
          float* dst = (bz == 0) ? e.outf : e.outf2;
          dst[(size_t)row * D_MOD + col] = val;
        }
      }
    }
  }
}

__global__ __launch_bounds__(512, 2) void k_qkv(const u16* __restrict__ A, const u16* __restrict__ B, EpiArgs e) {
  gemm256_body<0, 512, 8, 0, 6, 64>(A, B, e);
}
__global__ __launch_bounds__(512, 2) void k_ff1(const u16* __restrict__ A, const u16* __restrict__ B, EpiArgs e) {
  gemm256_body<2, 512, 8, 0, 8, 64>(A, B, e);
}
__global__ __launch_bounds__(512, 2) void k_ff2(const u16* __restrict__ A, const u16* __restrict__ B, EpiArgs e) {
  gemm256_body<4, 2048, 16, 1024, 2, 64>(A, B, e);
}

// ---------------- 128x128 GEMM for the O-projection (EPI1), verified structure ----------------
__global__ __launch_bounds__(256)
void k_proj(const u16* __restrict__ A, const u16* __restrict__ Bt,
            const float* __restrict__ bo, const float* __restrict__ add,
            const float* __restrict__ gate, float* __restrict__ outf) {
  __shared__ __align__(16) u16 As[128 * 64];
  __shared__ __align__(16) u16 Bs[128 * 64];
  const int tid = threadIdx.x;
  const int wid = tid >> 6, lane = tid & 63;
  const int wr = wid >> 1, wc = wid & 1;
  const int sub = lane >> 4, lc = lane & 15;
  const int K = 512;
  // XCD swizzle (grid 4 x 128 = 512 blocks)
  const int orig = (int)blockIdx.y * 4 + (int)blockIdx.x;
  const int wg = (orig & 7) * 64 + (orig >> 3);
  const int m0 = (wg >> 2) * 128, n0 = (wg & 3) * 128;

  f32x4 acc[4][4];
#pragma unroll
  for (int i = 0; i < 4; ++i)
#pragma unroll
    for (int j = 0; j < 4; ++j) acc[i][j] = (f32x4){0.f, 0.f, 0.f, 0.f};

  for (int k0 = 0; k0 < K; k0 += 64) {
#pragma unroll
    for (int i = 0; i < 4; ++i) {
      const int ldso = (wid * 4 + i) * 1024;
      const int o = ldso + lane * 16;
      const int r = o >> 7;
      const int c = (o & 127) >> 1;
      async16((char*)As + ldso, A  + (size_t)(m0 + r) * K + k0 + c);
      async16((char*)Bs + ldso, Bt + (size_t)(n0 + r) * K + k0 + c);
    }
    __syncthreads();
#pragma unroll
    for (int ks = 0; ks < 2; ++ks) {
      bf16x8 a[4], b[4];
#pragma unroll
      for (int i = 0; i < 4; ++i)
        a[i] = *reinterpret_cast<const bf16x8*>(&As[(wr * 64 + i * 16 + lc) * 64 + ks * 32 + sub * 8]);
#pragma unroll
      for (int j = 0; j < 4; ++j)
        b[j] = *reinterpret_cast<const bf16x8*>(&Bs[(wc * 64 + j * 16 + lc) * 64 + ks * 32 + sub * 8]);
#pragma unroll
      for (int i = 0; i < 4; ++i)
#pragma unroll
        for (int j = 0; j < 4; ++j) acc[i][j] = mfma16(a[i], b[j], acc[i][j]);
    }
    __syncthreads();
  }

#pragma unroll
  for (int i = 0; i < 4; ++i) {
    const int row0 = m0 + wr * 64 + i * 16 + sub * 4;
#pragma unroll
    for (int j = 0; j < 4; ++j) {
      const int col = n0 + wc * 64 + j * 16 + lc;
      f32x4 v = acc[i][j];
#pragma unroll
      for (int r = 0; r < 4; ++r) {
        const int row = row0 + r;
        outf[(size_t)row * D_MOD + col] =
            add[(size_t)row * D_MOD + col] + gate[row] * (v[r] + bo[col]);
      }
    }
  }
}

// ---------------- windowed attention: one block per (b,h, 64-query tile) ----------------
__global__ __launch_bounds__(256)
void attn_k(const u16* __restrict__ Q, const u16* __restrict__ Kt,
            const u16* __restrict__ V, u16* __restrict__ Oflat) {
  __shared__ __align__(16) u16 VT[64 * 192];
  __shared__ __align__(16) u16 P [64 * 192];
  __shared__ float tab[256];
  const int tid = threadIdx.x;
  const int wid = tid >> 6, lane = tid & 63;
  const int sub = lane >> 4, lc = lane & 15;
  const int qb = blockIdx.x, bh = blockIdx.y;
  const int bb = bh >> 3, hh = bh & 7;
  const int q0 = qb * 64, kstart = q0 - 64;
  const u16* Qb = Q  + (size_t)bh * S_LEN * D_HEAD;
  const u16* Kb = Kt + (size_t)bh * S_LEN * D_HEAD;
  const u16* Vb = V  + (size_t)bh * S_LEN * D_HEAD;

  if (tid < 255) {
    const int di = tid - 127;
    const float fd = (float)di;
    tab[tid] = (di >= -64 && di <= 64)
        ? expf(-fd * fd * 0.125f) + cosf(0.06283185307179586f * fd)
        : -1e9f;
  }

#pragma unroll
  for (int i = 0; i < 6; ++i) {
    const int c = tid + 256 * i;
    const int kk = c >> 3, dc = (c & 7) * 8;
    const int kg = kstart + kk;
    uint4 val = {0u, 0u, 0u, 0u};
    if (kg >= 0 && kg < S_LEN)
      val = *reinterpret_cast<const uint4*>(Vb + (size_t)kg * D_HEAD + dc);
    const u16* pv = reinterpret_cast<const u16*>(&val);
#pragma unroll
    for (int j = 0; j < 8; ++j)
      *reinterpret_cast<u16*>(reinterpret_cast<char*>(VT) + swz384(dc + j, kk * 2)) = pv[j];
  }

  bf16x8 qf[2];
#pragma unroll
  for (int ks = 0; ks < 2; ++ks)
    qf[ks] = *reinterpret_cast<const bf16x8*>(Qb + (size_t)(q0 + wid * 16 + lc) * D_HEAD + ks * 32 + sub * 8);

  f32x4 sc[12];
#pragma unroll
  for (int t = 0; t < 12; ++t) sc[t] = (f32x4){0.f, 0.f, 0.f, 0.f};
#pragma unroll
  for (int ks = 0; ks < 2; ++ks)
#pragma unroll
    for (int t = 0; t < 12; ++t) {
      int kg = kstart + t * 16 + lc;
      int kc = kg < 0 ? 0 : (kg > S_LEN - 1 ? S_LEN - 1 : kg);
      bf16x8 kf = *reinterpret_cast<const bf16x8*>(Kb + (size_t)kc * D_HEAD + ks * 32 + sub * 8);
      sc[t] = mfma16(qf[ks], kf, sc[t]);
    }
  __syncthreads();

  float rmax[4] = {-3e38f, -3e38f, -3e38f, -3e38f};
#pragma unroll
  for (int t = 0; t < 12; ++t) {
    const int kk = t * 16 + lc;
    const int kg = kstart + kk;
    const bool valid = (kg >= 0) && (kg < S_LEN);
#pragma unroll
    for (int r = 0; r < 4; ++r) {
      const int qrow = wid * 16 + sub * 4 + r;
      const float bias = valid ? tab[qrow - kk + 191] : -1e9f;
      const float sv = sc[t][r] * 0.125f + bias;
      sc[t][r] = sv;
      rmax[r] = fmaxf(rmax[r], sv);
    }
  }
#pragma unroll
  for (int m = 1; m < 16; m <<= 1)
#pragma unroll
    for (int r = 0; r < 4; ++r) rmax[r] = fmaxf(rmax[r], __shfl_xor(rmax[r], m));
  float rsum[4] = {0.f, 0.f, 0.f, 0.f};
#pragma unroll
  for (int t = 0; t < 12; ++t)
#pragma unroll
    for (int r = 0; r < 4; ++r) {
      const float p = expf(sc[t][r] - rmax[r]);
      sc[t][r] = p; rsum[r] += p;
    }
#pragma unroll
  for (int m = 1; m < 16; m <<= 1)
#pragma unroll
    for (int r = 0; r < 4; ++r) rsum[r] += __shfl_xor(rsum[r], m);
  float rinv[4];
#pragma unroll
  for (int r = 0; r < 4; ++r) rinv[r] = 1.0f / rsum[r];
#pragma unroll
  for (int t = 0; t < 12; ++t)
#pragma unroll
    for (int r = 0; r < 4; ++r) {
      const int qrow = wid * 16 + sub * 4 + r;
      *reinterpret_cast<u16*>(reinterpret_cast<char*>(P) + swz384(qrow, (t * 16 + lc) * 2))
          = f2bf(sc[t][r] * rinv[r]);
    }
  __syncthreads();

  f32x4 oacc[4];
#pragma unroll
  for (int t = 0; t < 4; ++t) oacc[t] = (f32x4){0.f, 0.f, 0.f, 0.f};
  const int arow = wid * 16 + lc;
#pragma unroll
  for (int ks = 0; ks < 6; ++ks) {
    const int bir = ks * 64 + sub * 16;
    bf16x8 pa = *reinterpret_cast<const bf16x8*>(reinterpret_cast<char*>(P) + swz384(arow, bir));
#pragma unroll
    for (int t = 0; t < 4; ++t) {
      bf16x8 vb = *reinterpret_cast<const bf16x8*>(reinterpret_cast<char*>(VT) + swz384(t * 16 + lc, bir));
      oacc[t] = mfma16(pa, vb, oacc[t]);
    }
  }

  const size_t obase = ((size_t)bb * S_LEN + q0) * D_MOD + hh * D_HEAD;
#pragma unroll
  for (int t = 0; t < 4; ++t)
#pragma unroll
    for (int r = 0; r < 4; ++r) {
      const int qrow = wid * 16 + sub * 4 + r;
      Oflat[obase + (size_t)qrow * D_MOD + t * 16 + lc] = f2bf(oacc[t][r]);
    }
}

// ---------------- launch ----------------
extern "C" void kernel_launch(void* const* d_in, const int* in_sizes, int n_in,
                              void* d_out, int out_size, void* d_ws, size_t ws_size,
                              hipStream_t stream) {
  (void)in_sizes; (void)n_in; (void)out_size; (void)ws_size;
  const float* src  = (const float*)d_in[0];
  const float* Wq   = (const float*)d_in[1];
  const float* bq   = (const float*)d_in[2];
  const float* Wk   = (const float*)d_in[3];
  const float* bk   = (const float*)d_in[4];
  const float* Wv   = (const float*)d_in[5];
  const float* bv   = (const float*)d_in[6];
  const float* Wo   = (const float*)d_in[7];
  const float* bo   = (const float*)d_in[8];
  const float* Wg   = (const float*)d_in[9];
  const float* bg   = (const float*)d_in[10];
  const float* W1   = (const float*)d_in[11];
  const float* b1   = (const float*)d_in[12];
  const float* W2   = (const float*)d_in[13];
  const float* b2   = (const float*)d_in[14];
  const float* ln1g = (const float*)d_in[15];
  const float* ln1b = (const float*)d_in[16];
  const float* ln2g = (const float*)d_in[17];
  const float* ln2b = (const float*)d_in[18];
  float* out = (float*)d_out;

  char* ws = (char*)d_ws;
  u16*   WqkvT  = (u16*)  (ws + 0);            //  1,572,864
  u16*   WoT    = (u16*)  (ws + 1572864);      //    524,288
  u16*   W1T    = (u16*)  (ws + 2097152);      //  2,097,152
  u16*   W2T    = (u16*)  (ws + 4194304);      //  2,097,152
  float* gatef  = (float*)(ws + 6291456);      //     65,536
  u16*   Xbf    = (u16*)  (ws + 6356992);      // 16,777,216  [dead after QKV]
  u16*   QKVbf  = (u16*)  (ws + 23134208);     // 50,331,648  [dead after attn]
  u16*   attnfl = (u16*)  (ws + 73465856);     // 16,777,216  [dead after proj]
  float* y1     = (float*)(ws + 90243072);     // 33,554,432  [dead after ln1]
  u16*   xbf2   = (u16*)  (ws + 123797504);    // 16,777,216  [live to end]
  u16*   hbuf   = Xbf;                         // 67,108,864 = Xbf+QKVbf regions (FF1 out)
  float* p0     = y1;                          // 33,554,432 (FF2 partial z=0)
  float* p1     = (float*)(ws + 140574720);    // 33,554,432 (FF2 partial z=1) -> 174,129,152

  // set once per call (idempotent; errors ignored — first, uncaptured, call sticks)
  (void)hipFuncSetAttribute((const void*)k_qkv, hipFuncAttributeMaxDynamicSharedMemorySize, 131072);
  (void)hipFuncSetAttribute((const void*)k_ff1, hipFuncAttributeMaxDynamicSharedMemorySize, 131072);
  (void)hipFuncSetAttribute((const void*)k_ff2, hipFuncAttributeMaxDynamicSharedMemorySize, 131072);

  dim3 tb(32, 8);
  cvt_gate<<<4096, 256, 0, stream>>>(src, Wg, bg, Xbf, gatef);
  transpose_cvt<<<dim3(16, 16), tb, 0, stream>>>(Wq, WqkvT,             512, 512);
  transpose_cvt<<<dim3(16, 16), tb, 0, stream>>>(Wk, WqkvT + 512 * 512, 512, 512);
  transpose_cvt<<<dim3(16, 16), tb, 0, stream>>>(Wv, WqkvT + 2 * 512 * 512, 512, 512);
  transpose_cvt<<<dim3(16, 16), tb, 0, stream>>>(Wo, WoT, 512, 512);
  transpose_cvt<<<dim3(64, 16), tb, 0, stream>>>(W1, W1T, 512, 2048);
  transpose_cvt<<<dim3(16, 64), tb, 0, stream>>>(W2, W2T, 2048, 512);

  EpiArgs e1{bq, bk, bv, nullptr, nullptr, nullptr, nullptr, QKVbf};
  k_qkv<<<dim3(6, 64, 1), 512, 131072, stream>>>(Xbf, WqkvT, e1);

  attn_k<<<dim3(32, 64), 256, 0, stream>>>(QKVbf, QKVbf + BHSD, QKVbf + 2 * BHSD, attnfl);

  k_proj<<<dim3(4, 128), 256, 0, stream>>>(attnfl, WoT, bo, src, gatef, y1);

  ln1_k<<<4096, 256, 0, stream>>>(y1, ln1g, ln1b, xbf2);

  EpiArgs e3{b1, nullptr, nullptr, nullptr, nullptr, nullptr, nullptr, hbuf};
  k_ff1<<<dim3(8, 64, 1), 512, 131072, stream>>>(xbf2, W1T, e3);

  EpiArgs e4{nullptr, nullptr, nullptr, nullptr, nullptr, p0, p1, nullptr};
  k_ff2<<<dim3(2, 64, 2), 512, 131072, stream>>>(hbuf, W2T, e4);

  ln2red_k<<<4096, 256, 0, stream>>>(xbf2, p0, p1, b2, ln2g, ln2b, out);
}

// Round 4
// 222.586 us; speedup vs baseline: 1.3863x; 1.0556x over previous
//
#include <hip/hip_runtime.h>
#include <hip/hip_bf16.h>
#include <math.h>

// Problem constants
#define S_LEN   2048
#define D_MOD   512
#define N_HEADS 8
#define D_HEAD  64
#define FF_DIM  2048
#define M_ROWS  16384            // B*S
#define BHSD    8388608          // 8*8*2048*64 elements per Q/K/V tensor

typedef __attribute__((ext_vector_type(8))) __bf16 bf16x8;
typedef __attribute__((ext_vector_type(4))) float  f32x4;
typedef unsigned short u16;

__device__ __forceinline__ u16 f2bf(float f) {           // RNE f32 -> bf16 bits
  unsigned u = __float_as_uint(f);
  u += 0x7fffu + ((u >> 16) & 1u);
  return (u16)(u >> 16);
}
__device__ __forceinline__ float bf2f(u16 h) { return __uint_as_float(((unsigned)h) << 16); }

__device__ __forceinline__ f32x4 mfma16(bf16x8 a, bf16x8 b, f32x4 c) {
  return __builtin_amdgcn_mfma_f32_16x16x32_bf16(a, b, c, 0, 0, 0);
}

// async global->LDS, 16B per lane; lds base wave-uniform (HW adds lane*16)
__device__ __forceinline__ void async16(void* lds, const void* g) {
  __builtin_amdgcn_global_load_lds(
      (const __attribute__((address_space(1))) unsigned int*)g,
      (__attribute__((address_space(3))) unsigned int*)lds, 16, 0, 0);
}

#define BAR()    asm volatile("s_barrier" ::: "memory")
#define WAITV(n) asm volatile("s_waitcnt vmcnt(" #n ")" ::: "memory")
#define WAITL()  asm volatile("s_waitcnt lgkmcnt(0)" ::: "memory")

// XOR swizzle within each 128B group of a 384B row (attn 64x192 bf16 tiles)
__device__ __forceinline__ int swz384(int row, int bir) {
  return row * 384 + ((bir & ~127) | ((bir ^ ((row & 7) << 4)) & 127));
}

// ---------------- fused src->bf16 + gate, one wave per row ----------------
__global__ __launch_bounds__(256) void cvt_gate(const float* __restrict__ src,
                                                const float* __restrict__ Wg,
                                                const float* __restrict__ bg,
                                                u16* __restrict__ xb,
                                                float* __restrict__ gate) {
  const int wid = threadIdx.x >> 6, lane = threadIdx.x & 63;
  const size_t row = (size_t)blockIdx.x * 4 + wid;
  const float4* s = reinterpret_cast<const float4*>(src + row * D_MOD);
  const float4* w = reinterpret_cast<const float4*>(Wg);
  float4 a0 = s[lane * 2], a1 = s[lane * 2 + 1];
  float4 w0 = w[lane * 2], w1 = w[lane * 2 + 1];
  float acc = a0.x * w0.x + a0.y * w0.y + a0.z * w0.z + a0.w * w0.w +
              a1.x * w1.x + a1.y * w1.y + a1.z * w1.z + a1.w * w1.w;
#pragma unroll
  for (int m = 1; m < 64; m <<= 1) acc += __shfl_xor(acc, m);
  ushort4 h0, h1;
  h0.x = f2bf(a0.x); h0.y = f2bf(a0.y); h0.z = f2bf(a0.z); h0.w = f2bf(a0.w);
  h1.x = f2bf(a1.x); h1.y = f2bf(a1.y); h1.z = f2bf(a1.z); h1.w = f2bf(a1.w);
  ushort4* ob = reinterpret_cast<ushort4*>(xb + row * D_MOD);
  ob[lane * 2] = h0; ob[lane * 2 + 1] = h1;
  if (lane == 0) {
    float g = 1.f / (1.f + __expf(-(acc + bg[0])));
    gate[row] = g > 0.f ? g : 0.f;    // THRESH = 0
  }
}

// ---------------- [K,N] f32 -> [N,K] bf16 transpose ----------------
__global__ void transpose_cvt(const float* __restrict__ in, u16* __restrict__ out,
                              int K, int N) {
  __shared__ float t[32][33];
  const int n0 = blockIdx.x * 32, k0 = blockIdx.y * 32;
  const int tx = threadIdx.x, ty = threadIdx.y;   // (32,8)
#pragma unroll
  for (int i = 0; i < 4; ++i)
    t[ty + 8 * i][tx] = in[(size_t)(k0 + ty + 8 * i) * N + n0 + tx];
  __syncthreads();
#pragma unroll
  for (int i = 0; i < 4; ++i)
    out[(size_t)(n0 + ty + 8 * i) * K + k0 + tx] = f2bf(t[tx][ty + 8 * i]);
}

// ------ fused proj split-K reduce + bias + gate + residual + layernorm 1 ------
__global__ __launch_bounds__(256) void ln1red_k(const float* __restrict__ src,
                                                const float* __restrict__ gate,
                                                const u16* __restrict__ p0,
                                                const u16* __restrict__ p1,
                                                const float* __restrict__ bo,
                                                const float* __restrict__ gam,
                                                const float* __restrict__ bet,
                                                u16* __restrict__ outb) {
  const int wid = threadIdx.x >> 6, lane = threadIdx.x & 63;
  const size_t row = (size_t)blockIdx.x * 4 + wid;
  const size_t base = row * D_MOD;
  const float g = gate[row];
  const float4*  sp = reinterpret_cast<const float4*>(src + base);
  const ushort4* a  = reinterpret_cast<const ushort4*>(p0 + base);
  const ushort4* c  = reinterpret_cast<const ushort4*>(p1 + base);
  const float4*  bb = reinterpret_cast<const float4*>(bo);
  float4 s0 = sp[lane * 2], s1 = sp[lane * 2 + 1];
  ushort4 a0 = a[lane * 2], a1 = a[lane * 2 + 1];
  ushort4 c0 = c[lane * 2], c1 = c[lane * 2 + 1];
  float4 d0 = bb[lane * 2], d1 = bb[lane * 2 + 1];
  float4 v0, v1;
  v0.x = s0.x + g * (bf2f(a0.x) + bf2f(c0.x) + d0.x);
  v0.y = s0.y + g * (bf2f(a0.y) + bf2f(c0.y) + d0.y);
  v0.z = s0.z + g * (bf2f(a0.z) + bf2f(c0.z) + d0.z);
  v0.w = s0.w + g * (bf2f(a0.w) + bf2f(c0.w) + d0.w);
  v1.x = s1.x + g * (bf2f(a1.x) + bf2f(c1.x) + d1.x);
  v1.y = s1.y + g * (bf2f(a1.y) + bf2f(c1.y) + d1.y);
  v1.z = s1.z + g * (bf2f(a1.z) + bf2f(c1.z) + d1.z);
  v1.w = s1.w + g * (bf2f(a1.w) + bf2f(c1.w) + d1.w);
  float s  = v0.x + v0.y + v0.z + v0.w + v1.x + v1.y + v1.z + v1.w;
  float s2 = v0.x * v0.x + v0.y * v0.y + v0.z * v0.z + v0.w * v0.w +
             v1.x * v1.x + v1.y * v1.y + v1.z * v1.z + v1.w * v1.w;
#pragma unroll
  for (int m = 1; m < 64; m <<= 1) { s += __shfl_xor(s, m); s2 += __shfl_xor(s2, m); }
  const float mu = s * (1.0f / 512.0f);
  const float var = s2 * (1.0f / 512.0f) - mu * mu;
  const float rs = 1.0f / sqrtf(var + 1e-5f);
  const float4* gp = reinterpret_cast<const float4*>(gam);
  const float4* bp = reinterpret_cast<const float4*>(bet);
  float4 g0 = gp[lane * 2], g1 = gp[lane * 2 + 1];
  float4 e0 = bp[lane * 2], e1 = bp[lane * 2 + 1];
  ushort4 h0, h1;
  h0.x = f2bf((v0.x - mu) * rs * g0.x + e0.x);  h0.y = f2bf((v0.y - mu) * rs * g0.y + e0.y);
  h0.z = f2bf((v0.z - mu) * rs * g0.z + e0.z);  h0.w = f2bf((v0.w - mu) * rs * g0.w + e0.w);
  h1.x = f2bf((v1.x - mu) * rs * g1.x + e1.x);  h1.y = f2bf((v1.y - mu) * rs * g1.y + e1.y);
  h1.z = f2bf((v1.z - mu) * rs * g1.z + e1.z);  h1.w = f2bf((v1.w - mu) * rs * g1.w + e1.w);
  ushort4* ob = reinterpret_cast<ushort4*>(outb + base);
  ob[lane * 2] = h0; ob[lane * 2 + 1] = h1;
}

// ---------------- fused FF2 split-K reduce + bias + residual + layernorm 2 ----------------
__global__ __launch_bounds__(256) void ln2red_k(const u16* __restrict__ xb,
                                                const u16* __restrict__ p0,
                                                const u16* __restrict__ p1,
                                                const float* __restrict__ b2,
                                                const float* __restrict__ gam,
                                                const float* __restrict__ bet,
                                                float* __restrict__ out) {
  const int wid = threadIdx.x >> 6, lane = threadIdx.x & 63;
  const size_t row = (size_t)blockIdx.x * 4 + wid;
  const size_t base = row * D_MOD;
  const ushort4* xp = reinterpret_cast<const ushort4*>(xb + base);
  const ushort4* q0 = reinterpret_cast<const ushort4*>(p0 + base);
  const ushort4* q1 = reinterpret_cast<const ushort4*>(p1 + base);
  const float4* bb = reinterpret_cast<const float4*>(b2);
  ushort4 h0 = xp[lane * 2], h1 = xp[lane * 2 + 1];
  ushort4 a0 = q0[lane * 2], a1 = q0[lane * 2 + 1];
  ushort4 c0 = q1[lane * 2], c1 = q1[lane * 2 + 1];
  float4 d0 = bb[lane * 2], d1 = bb[lane * 2 + 1];
  float4 v0, v1;
  v0.x = bf2f(h0.x) + bf2f(a0.x) + bf2f(c0.x) + d0.x;
  v0.y = bf2f(h0.y) + bf2f(a0.y) + bf2f(c0.y) + d0.y;
  v0.z = bf2f(h0.z) + bf2f(a0.z) + bf2f(c0.z) + d0.z;
  v0.w = bf2f(h0.w) + bf2f(a0.w) + bf2f(c0.w) + d0.w;
  v1.x = bf2f(h1.x) + bf2f(a1.x) + bf2f(c1.x) + d1.x;
  v1.y = bf2f(h1.y) + bf2f(a1.y) + bf2f(c1.y) + d1.y;
  v1.z = bf2f(h1.z) + bf2f(a1.z) + bf2f(c1.z) + d1.z;
  v1.w = bf2f(h1.w) + bf2f(a1.w) + bf2f(c1.w) + d1.w;
  float s  = v0.x + v0.y + v0.z + v0.w + v1.x + v1.y + v1.z + v1.w;
  float s2 = v0.x * v0.x + v0.y * v0.y + v0.z * v0.z + v0.w * v0.w +
             v1.x * v1.x + v1.y * v1.y + v1.z * v1.z + v1.w * v1.w;
#pragma unroll
  for (int m = 1; m < 64; m <<= 1) { s += __shfl_xor(s, m); s2 += __shfl_xor(s2, m); }
  const float mu = s * (1.0f / 512.0f);
  const float var = s2 * (1.0f / 512.0f) - mu * mu;
  const float rs = 1.0f / sqrtf(var + 1e-5f);
  const float4* gp = reinterpret_cast<const float4*>(gam);
  const float4* bp = reinterpret_cast<const float4*>(bet);
  float4 g0 = gp[lane * 2], g1 = gp[lane * 2 + 1];
  float4 e0 = bp[lane * 2], e1 = bp[lane * 2 + 1];
  float4 o0, o1;
  o0.x = (v0.x - mu) * rs * g0.x + e0.x;  o0.y = (v0.y - mu) * rs * g0.y + e0.y;
  o0.z = (v0.z - mu) * rs * g0.z + e0.z;  o0.w = (v0.w - mu) * rs * g0.w + e0.w;
  o1.x = (v1.x - mu) * rs * g1.x + e1.x;  o1.y = (v1.y - mu) * rs * g1.y + e1.y;
  o1.z = (v1.z - mu) * rs * g1.z + e1.z;  o1.w = (v1.w - mu) * rs * g1.w + e1.w;
  float4* q = reinterpret_cast<float4*>(out + base);
  q[lane * 2] = o0; q[lane * 2 + 1] = o1;
}

// ---------------- 256x256 deep-pipelined GEMM: C = A[M,K] @ Bt[N,K]^T ----------------
struct EpiArgs {
  const float* b0; const float* b1; const float* b2;   // biases
  float* outf; u16* outb; u16* outb2;
};

// EPI: 0 = QKV bias+scatter->bf16[3][B,H,S,dh]   2 = relu(acc+b1)->bf16 [M,2048]
//      4 = raw bf16 partial -> outb (bz=0) / outb2 (bz=1), stride 512
template<int EPI, int LD, int NT, int KSLICE, int GX, int GY>
__device__ __forceinline__ void gemm256_body(const u16* __restrict__ A,
                                             const u16* __restrict__ Bt, EpiArgs e) {
  extern __shared__ char smem[];
  char* Asb = smem;            // [2 buf][256 rows][128 B], row-swizzled via source
  char* Bsb = smem + 65536;
  const int tid = threadIdx.x;
  const int wid = tid >> 6, lane = tid & 63;
  const int sub = lane >> 4, lc = lane & 15;
  const int wr = wid >> 2, wcn = wid & 3;

  // flatten + bijective XCD swizzle (all grids are multiples of 8 blocks)
  const int nwg = (int)(gridDim.x * gridDim.y * gridDim.z);
  const int orig = ((int)blockIdx.z * (int)gridDim.y + (int)blockIdx.y) * (int)gridDim.x + (int)blockIdx.x;
  const int cpx = nwg >> 3;
  const int wg = (orig & 7) * cpx + (orig >> 3);
  const int bx = wg % GX;
  const int by = (wg / GX) % GY;
  const int bz = wg / (GX * GY);
  const int m0 = by * 256, n0 = bx * 256;
  const int kb = KSLICE * bz;

  const u16* Ab = A + (size_t)m0 * LD;
  const u16* Bb = Bt + (size_t)n0 * LD;

  f32x4 acc[8][4];
#pragma unroll
  for (int i = 0; i < 8; ++i)
#pragma unroll
    for (int j = 0; j < 4; ++j) acc[i][j] = (f32x4){0.f, 0.f, 0.f, 0.f};

  const int lr0 = tid >> 3;   // 0..63
  const int sl  = tid & 7;

  // stage one 256x64 bf16 tile (A or B): 4 x async16 per thread, source pre-swizzled
#define STAGE(BASE, SRC, BUF, KT)                                              \
  {                                                                            \
    const int kk_ = kb + (KT) * 64;                                            \
    _Pragma("unroll")                                                          \
    for (int r_ = 0; r_ < 4; ++r_) {                                           \
      const int lr_ = r_ * 64 + lr0;                                           \
      async16((BASE) + (BUF) * 32768 + r_ * 8192 + wid * 1024,                 \
              (SRC) + (size_t)lr_ * LD + kk_ + ((sl ^ (lr_ & 7)) << 3));       \
    }                                                                          \
  }
#define LDFRAG(BASE, ROW, KS) \
  (*reinterpret_cast<const bf16x8*>((BASE) + (ROW) * 128 + ((((KS) * 64) + sub * 16) ^ (((ROW) & 7) << 4))))

  // prologue: B0,A0,B1,A1 (issue order matters for vmcnt counting)
  STAGE(Bsb, Bb, 0, 0);
  STAGE(Asb, Ab, 0, 0);
  STAGE(Bsb, Bb, 1, 1);
  STAGE(Asb, Ab, 1, 1);
  WAITV(8);            // tile 0 landed, tile 1's 8 loads still in flight
  BAR();

  for (int t = 0; t < NT; ++t) {
    const int buf = t & 1;
    char* Abl = Asb + buf * 32768;
    char* Bbl = Bsb + buf * 32768;
    bf16x8 af[4][2], bfr[2][2][2];   // af: qr-half of A; bfr[qc][fc][ks]
    // ---- ph1: read A qr0 (8) + B qc0 (4); MFMA (qr0,qc0) ----
#pragma unroll
    for (int f = 0; f < 4; ++f) {
      const int row = wr * 128 + f * 16 + lc;
#pragma unroll
      for (int ks = 0; ks < 2; ++ks) af[f][ks] = LDFRAG(Abl, row, ks);
    }
#pragma unroll
    for (int f = 0; f < 2; ++f) {
      const int row = wcn * 64 + f * 16 + lc;
#pragma unroll
      for (int ks = 0; ks < 2; ++ks) bfr[0][f][ks] = LDFRAG(Bbl, row, ks);
    }
    __builtin_amdgcn_s_setprio(1);
#pragma unroll
    for (int f = 0; f < 4; ++f)
#pragma unroll
      for (int c = 0; c < 2; ++c)
#pragma unroll
        for (int ks = 0; ks < 2; ++ks)
          acc[f][c] = mfma16(af[f][ks], bfr[0][c][ks], acc[f][c]);
    __builtin_amdgcn_s_setprio(0);
    BAR();
    // ---- ph2: read B qc1 (4); MFMA (qr0,qc1) ----
#pragma unroll
    for (int f = 0; f < 2; ++f) {
      const int row = wcn * 64 + 32 + f * 16 + lc;
#pragma unroll
      for (int ks = 0; ks < 2; ++ks) bfr[1][f][ks] = LDFRAG(Bbl, row, ks);
    }
    __builtin_amdgcn_s_setprio(1);
#pragma unroll
    for (int f = 0; f < 4; ++f)
#pragma unroll
      for (int c = 0; c < 2; ++c)
#pragma unroll
        for (int ks = 0; ks < 2; ++ks)
          acc[f][2 + c] = mfma16(af[f][ks], bfr[1][c][ks], acc[f][2 + c]);
    __builtin_amdgcn_s_setprio(0);
    WAITL();           // all B (and A) LDS reads landed in regs before B region is re-staged
    BAR();
    // ---- ph3: stage B(t+2) into this buf; read A qr1 (8); MFMA (qr1,qc1) ----
    if (t + 2 < NT) STAGE(Bsb, Bb, buf, t + 2);
#pragma unroll
    for (int f = 0; f < 4; ++f) {
      const int row = wr * 128 + 64 + f * 16 + lc;
#pragma unroll
      for (int ks = 0; ks < 2; ++ks) af[f][ks] = LDFRAG(Abl, row, ks);
    }
    __builtin_amdgcn_s_setprio(1);
#pragma unroll
    for (int f = 0; f < 4; ++f)
#pragma unroll
      for (int c = 0; c < 2; ++c)
#pragma unroll
        for (int ks = 0; ks < 2; ++ks)
          acc[4 + f][2 + c] = mfma16(af[f][ks], bfr[1][c][ks], acc[4 + f][2 + c]);
    __builtin_amdgcn_s_setprio(0);
    WAITL();           // A qr1 reads landed before A region is re-staged
    BAR();
    // ---- ph4: stage A(t+2); MFMA (qr1,qc0); counted boundary wait ----
    if (t + 2 < NT) STAGE(Asb, Ab, buf, t + 2);
    __builtin_amdgcn_s_setprio(1);
#pragma unroll
    for (int f = 0; f < 4; ++f)
#pragma unroll
      for (int c = 0; c < 2; ++c)
#pragma unroll
        for (int ks = 0; ks < 2; ++ks)
          acc[4 + f][c] = mfma16(af[f][ks], bfr[0][c][ks], acc[4 + f][c]);
    __builtin_amdgcn_s_setprio(0);
    if (t + 1 < NT) {
      if (t + 2 < NT) { WAITV(8); } else { WAITV(0); }  // leave next-next tile in flight
      BAR();
    }
  }
#undef STAGE
#undef LDFRAG

  // epilogue
#pragma unroll
  for (int fr = 0; fr < 8; ++fr) {
    const int row0 = m0 + wr * 128 + fr * 16 + sub * 4;
#pragma unroll
    for (int fc = 0; fc < 4; ++fc) {
      const int col = n0 + wcn * 64 + fc * 16 + lc;
      f32x4 v = acc[fr][fc];
#pragma unroll
      for (int i = 0; i < 4; ++i) {
        const int row = row0 + i;
        const float val = v[i];
        if constexpr (EPI == 0) {
          const int which = col >> 9, nn = col & 511;
          const int hh = nn >> 6, dd = nn & 63;
          const float* bp = (which == 0) ? e.b0 : (which == 1) ? e.b1 : e.b2;
          const int bb = row >> 11, ss = row & 2047;
          e.outb[(size_t)which * BHSD + (((size_t)bb * N_HEADS + hh) * S_LEN + ss) * D_HEAD + dd]
              = f2bf(val + bp[nn]);
        } else if constexpr (EPI == 2) {
          float o = val + e.b0[col];
          e.outb[(size_t)row * FF_DIM + col] = f2bf(o > 0.f ? o : 0.f);
        } else {
          u16* dst = (bz == 0) ? e.outb : e.outb2;
          dst[(size_t)row * D_MOD + col] = f2bf(val);
        }
      }
    }
  }
}

__global__ __launch_bounds__(512, 2) void k_qkv(const u16* __restrict__ A, const u16* __restrict__ B, EpiArgs e) {
  gemm256_body<0, 512, 8, 0, 6, 64>(A, B, e);
}
__global__ __launch_bounds__(512, 2) void k_ff1(const u16* __restrict__ A, const u16* __restrict__ B, EpiArgs e) {
  gemm256_body<2, 512, 8, 0, 8, 64>(A, B, e);
}
__global__ __launch_bounds__(512, 2) void k_ff2(const u16* __restrict__ A, const u16* __restrict__ B, EpiArgs e) {
  gemm256_body<4, 2048, 16, 1024, 2, 64>(A, B, e);
}
__global__ __launch_bounds__(512, 2) void k_proj(const u16* __restrict__ A, const u16* __restrict__ B, EpiArgs e) {
  gemm256_body<4, 512, 4, 256, 2, 64>(A, B, e);
}

// ---------------- windowed attention: one block per (b,h, 64-query tile) ----------------
// R2-proven structure (swz384 LDS layout, plain b128 fragment reads); fast-math exp/cos.
__global__ __launch_bounds__(256)
void attn_k(const u16* __restrict__ Q, const u16* __restrict__ Kt,
            const u16* __restrict__ V, u16* __restrict__ Oflat) {
  __shared__ __align__(16) u16 VT[64 * 192];   // V^T (swizzled): row=d, col=key
  __shared__ __align__(16) u16 P [64 * 192];   // probs (swizzled): row=q, col=key
  __shared__ float tab[256];                   // bias table indexed by dist+127
  const int tid = threadIdx.x;
  const int wid = tid >> 6, lane = tid & 63;
  const int sub = lane >> 4, lc = lane & 15;
  const int qb = blockIdx.x, bh = blockIdx.y;
  const int bb = bh >> 3, hh = bh & 7;
  const int q0 = qb * 64, kstart = q0 - 64;    // 192-key band
  const u16* Qb = Q  + (size_t)bh * S_LEN * D_HEAD;
  const u16* Kb = Kt + (size_t)bh * S_LEN * D_HEAD;
  const u16* Vb = V  + (size_t)bh * S_LEN * D_HEAD;

  if (tid < 255) {                             // dist in [-127,127]
    const int di = tid - 127;
    const float fd = (float)di;
    tab[tid] = (di >= -64 && di <= 64)
        ? __expf(-fd * fd * 0.125f) + __cosf(0.06283185307179586f * fd)
        : -1e9f;
  }

  // stage V^T (zero-fill out-of-range keys)
#pragma unroll
  for (int i = 0; i < 6; ++i) {
    const int c = tid + 256 * i;               // 1536 chunks of 8 elements
    const int kk = c >> 3, dc = (c & 7) * 8;
    const int kg = kstart + kk;
    uint4 val = {0u, 0u, 0u, 0u};
    if (kg >= 0 && kg < S_LEN)
      val = *reinterpret_cast<const uint4*>(Vb + (size_t)kg * D_HEAD + dc);
    const u16* pv = reinterpret_cast<const u16*>(&val);
#pragma unroll
    for (int j = 0; j < 8; ++j)
      *reinterpret_cast<u16*>(reinterpret_cast<char*>(VT) + swz384(dc + j, kk * 2)) = pv[j];
  }

  // Q fragments straight from global (A operand: row = lane&15)
  bf16x8 qf[2];
#pragma unroll
  for (int ks = 0; ks < 2; ++ks)
    qf[ks] = *reinterpret_cast<const bf16x8*>(Qb + (size_t)(q0 + wid * 16 + lc) * D_HEAD + ks * 32 + sub * 8);

  // QK^T: 12 col tiles of 16 keys, K fragments straight from global (clamped; masked later)
  f32x4 sc[12];
#pragma unroll
  for (int t = 0; t < 12; ++t) sc[t] = (f32x4){0.f, 0.f, 0.f, 0.f};
#pragma unroll
  for (int ks = 0; ks < 2; ++ks)
#pragma unroll
    for (int t = 0; t < 12; ++t) {
      int kg = kstart + t * 16 + lc;
      int kc = kg < 0 ? 0 : (kg > S_LEN - 1 ? S_LEN - 1 : kg);
      bf16x8 kf = *reinterpret_cast<const bf16x8*>(Kb + (size_t)kc * D_HEAD + ks * 32 + sub * 8);
      sc[t] = mfma16(qf[ks], kf, sc[t]);
    }
  __syncthreads();   // tab + VT ready

  // bias + mask + wave-parallel softmax (row lives across 16 lanes x 12 regs)
  float rmax[4] = {-3e38f, -3e38f, -3e38f, -3e38f};
#pragma unroll
  for (int t = 0; t < 12; ++t) {
    const int kk = t * 16 + lc;
    const int kg = kstart + kk;
    const bool valid = (kg >= 0) && (kg < S_LEN);
#pragma unroll
    for (int r = 0; r < 4; ++r) {
      const int qrow = wid * 16 + sub * 4 + r;
      const float bias = valid ? tab[qrow - kk + 191] : -1e9f;
      const float sv = sc[t][r] * 0.125f + bias;   // 1/sqrt(64)
      sc[t][r] = sv;
      rmax[r] = fmaxf(rmax[r], sv);
    }
  }
#pragma unroll
  for (int m = 1; m < 16; m <<= 1)
#pragma unroll
    for (int r = 0; r < 4; ++r) rmax[r] = fmaxf(rmax[r], __shfl_xor(rmax[r], m));
  float rsum[4] = {0.f, 0.f, 0.f, 0.f};
#pragma unroll
  for (int t = 0; t < 12; ++t)
#pragma unroll
    for (int r = 0; r < 4; ++r) {
      const float p = __expf(sc[t][r] - rmax[r]);
      sc[t][r] = p; rsum[r] += p;
    }
#pragma unroll
  for (int m = 1; m < 16; m <<= 1)
#pragma unroll
    for (int r = 0; r < 4; ++r) rsum[r] += __shfl_xor(rsum[r], m);
  float rinv[4];
#pragma unroll
  for (int r = 0; r < 4; ++r) rinv[r] = 1.0f / rsum[r];
#pragma unroll
  for (int t = 0; t < 12; ++t)
#pragma unroll
    for (int r = 0; r < 4; ++r) {
      const int qrow = wid * 16 + sub * 4 + r;
      *reinterpret_cast<u16*>(reinterpret_cast<char*>(P) + swz384(qrow, (t * 16 + lc) * 2))
          = f2bf(sc[t][r] * rinv[r]);
    }
  __syncthreads();   // P + VT consumable

  // PV: out[64q][64d], K-dim = 192 keys
  f32x4 oacc[4];
#pragma unroll
  for (int t = 0; t < 4; ++t) oacc[t] = (f32x4){0.f, 0.f, 0.f, 0.f};
  const int arow = wid * 16 + lc;
#pragma unroll
  for (int ks = 0; ks < 6; ++ks) {
    const int bir = ks * 64 + sub * 16;
    bf16x8 pa = *reinterpret_cast<const bf16x8*>(reinterpret_cast<char*>(P) + swz384(arow, bir));
#pragma unroll
    for (int t = 0; t < 4; ++t) {
      bf16x8 vb = *reinterpret_cast<const bf16x8*>(reinterpret_cast<char*>(VT) + swz384(t * 16 + lc, bir));
      oacc[t] = mfma16(pa, vb, oacc[t]);
    }
  }

  // write to [B,S,H*dh] bf16
  const size_t obase = ((size_t)bb * S_LEN + q0) * D_MOD + hh * D_HEAD;
#pragma unroll
  for (int t = 0; t < 4; ++t)
#pragma unroll
    for (int r = 0; r < 4; ++r) {
      const int qrow = wid * 16 + sub * 4 + r;
      Oflat[obase + (size_t)qrow * D_MOD + t * 16 + lc] = f2bf(oacc[t][r]);
    }
}

// ---------------- launch ----------------
extern "C" void kernel_launch(void* const* d_in, const int* in_sizes, int n_in,
                              void* d_out, int out_size, void* d_ws, size_t ws_size,
                              hipStream_t stream) {
  (void)in_sizes; (void)n_in; (void)out_size; (void)ws_size;
  const float* src  = (const float*)d_in[0];
  const float* Wq   = (const float*)d_in[1];
  const float* bq   = (const float*)d_in[2];
  const float* Wk   = (const float*)d_in[3];
  const float* bk   = (const float*)d_in[4];
  const float* Wv   = (const float*)d_in[5];
  const float* bv   = (const float*)d_in[6];
  const float* Wo   = (const float*)d_in[7];
  const float* bo   = (const float*)d_in[8];
  const float* Wg   = (const float*)d_in[9];
  const float* bg   = (const float*)d_in[10];
  const float* W1   = (const float*)d_in[11];
  const float* b1   = (const float*)d_in[12];
  const float* W2   = (const float*)d_in[13];
  const float* b2   = (const float*)d_in[14];
  const float* ln1g = (const float*)d_in[15];
  const float* ln1b = (const float*)d_in[16];
  const float* ln2g = (const float*)d_in[17];
  const float* ln2b = (const float*)d_in[18];
  float* out = (float*)d_out;

  char* ws = (char*)d_ws;
  u16*   WqkvT  = (u16*)  (ws + 0);            //  1,572,864
  u16*   WoT    = (u16*)  (ws + 1572864);      //    524,288
  u16*   W1T    = (u16*)  (ws + 2097152);      //  2,097,152
  u16*   W2T    = (u16*)  (ws + 4194304);      //  2,097,152
  float* gatef  = (float*)(ws + 6291456);      //     65,536
  u16*   Xbf    = (u16*)  (ws + 6356992);      // 16,777,216  [dead after QKV]
  u16*   QKVbf  = (u16*)  (ws + 23134208);     // 50,331,648  [dead after attn]
  u16*   attnfl = (u16*)  (ws + 73465856);     // 16,777,216  [dead after proj]
  u16*   pr0    = (u16*)  (ws + 90243072);     // 16,777,216  (proj/ff2 partial z=0)
  u16*   pr1    = (u16*)  (ws + 107020288);    // 16,777,216  (proj/ff2 partial z=1)
  u16*   xbf2   = (u16*)  (ws + 123797504);    // 16,777,216  [live to end] -> 140,574,720 total
  u16*   hbuf   = Xbf;                         // FF1 out: 67,108,864 = Xbf+QKVbf regions (dead)
  u16*   pf0    = pr0;                         // FF2 partials reuse proj partials (dead after ln1red)
  u16*   pf1    = pr1;

  // set once per call (idempotent; errors ignored — first, uncaptured, call sticks)
  (void)hipFuncSetAttribute((const void*)k_qkv,  hipFuncAttributeMaxDynamicSharedMemorySize, 131072);
  (void)hipFuncSetAttribute((const void*)k_ff1,  hipFuncAttributeMaxDynamicSharedMemorySize, 131072);
  (void)hipFuncSetAttribute((const void*)k_ff2,  hipFuncAttributeMaxDynamicSharedMemorySize, 131072);
  (void)hipFuncSetAttribute((const void*)k_proj, hipFuncAttributeMaxDynamicSharedMemorySize, 131072);

  dim3 tb(32, 8);
  cvt_gate<<<4096, 256, 0, stream>>>(src, Wg, bg, Xbf, gatef);
  transpose_cvt<<<dim3(16, 16), tb, 0, stream>>>(Wq, WqkvT,             512, 512);
  transpose_cvt<<<dim3(16, 16), tb, 0, stream>>>(Wk, WqkvT + 512 * 512, 512, 512);
  transpose_cvt<<<dim3(16, 16), tb, 0, stream>>>(Wv, WqkvT + 2 * 512 * 512, 512, 512);
  transpose_cvt<<<dim3(16, 16), tb, 0, stream>>>(Wo, WoT, 512, 512);
  transpose_cvt<<<dim3(64, 16), tb, 0, stream>>>(W1, W1T, 512, 2048);
  transpose_cvt<<<dim3(16, 64), tb, 0, stream>>>(W2, W2T, 2048, 512);

  EpiArgs e1{bq, bk, bv, nullptr, QKVbf, nullptr};
  k_qkv<<<dim3(6, 64, 1), 512, 131072, stream>>>(Xbf, WqkvT, e1);

  attn_k<<<dim3(32, 64), 256, 0, stream>>>(QKVbf, QKVbf + BHSD, QKVbf + 2 * BHSD, attnfl);

  EpiArgs e2{nullptr, nullptr, nullptr, nullptr, pr0, pr1};
  k_proj<<<dim3(2, 64, 2), 512, 131072, stream>>>(attnfl, WoT, e2);

  ln1red_k<<<4096, 256, 0, stream>>>(src, gatef, pr0, pr1, bo, ln1g, ln1b, xbf2);

  EpiArgs e3{b1, nullptr, nullptr, nullptr, hbuf, nullptr};
  k_ff1<<<dim3(8, 64, 1), 512, 131072, stream>>>(xbf2, W1T, e3);

  EpiArgs e4{nullptr, nullptr, nullptr, nullptr, pf0, pf1};
  k_ff2<<<dim3(2, 64, 2), 512, 131072, stream>>>(hbuf, W2T, e4);

  ln2red_k<<<4096, 256, 0, stream>>>(xbf2, pf0, pf1, b2, ln2g, ln2b, out);
}